// Round 8
// baseline (199.772 us; speedup 1.0000x reference)
//
#include <hip/hip_runtime.h>

#define NN 100000
#define NE 1600000
#define TT 12
#define HH 32
#define NB 391          // coarse buckets of 256 nodes (node bucket = d >> 8)
#define BSH 8
#define GCS 16          // gcursor stride (ints) = one 64B line per cursor
#define CHUNK 4096      // edges per scatter block
#define LOG2E 1.4426950408889634f

typedef unsigned int u32;

// ---------------- workspace layout (4-byte units), ~17 MB ----------------
// [0, 400)             : bstart[392]
// [400, 800)           : cnt[391]      (zeroed by k_zero)
// [800, 816)           : done flag     (zeroed by k_zero)
// [816, 7072)          : gcursor (x16 padded)
// [107088, 207088)     : dinv (float)
// [207104, 1007104)    : xpb (u32[NN][8]) = bf16x2-packed dinv[n]*x[n], 32B rows
//                        (3.2MB -> L2-resident per XCD)
// [1007104, 4207104)   : rec (int2[NE]) — bucket-grouped, NOT node-sorted
// [4207104, 4207248)   : P params: Az[32],Bz[32],Ah2[32],Bh2[32],probs[12]
//                        (gate params pre-scaled by log2e for raw v_exp_f32)
// NOTE: the ~41us __amd_rocclr_fillBufferAligned dispatches in rocprof are the
// harness's 256MiB workspace re-poison (reset phase) — NOT in the timed window.

__global__ __launch_bounds__(512) void k_zero(int* __restrict__ ws32) {
    int t = threadIdx.x;
    if (t < 416) ws32[400 + t] = 0;   // cnt[391] + pad + done
}

// Bucket histogram; the LAST block to finish (global done counter) then does
// the bucket scan + gate-param folding in the same launch.
// NOTE: per-edge GLOBAL float atomics are catastrophic on gfx950 (R2: 90us,
// WRITE_SIZE == 1.6M x 32B -> uncached fabric writes). LDS atomics only.
__global__ __launch_bounds__(256) void k_pre(const int* __restrict__ ei,
                                             int* __restrict__ cnt,
                                             int* __restrict__ done,
                                             int* __restrict__ bstart,
                                             int* __restrict__ gcursor,
                                             const float* __restrict__ czw, const float* __restrict__ czb,
                                             const float* __restrict__ lzw, const float* __restrict__ lzb,
                                             const float* __restrict__ chw, const float* __restrict__ chb,
                                             const float* __restrict__ lhw, const float* __restrict__ lhb,
                                             const float* __restrict__ att, float* __restrict__ P) {
    __shared__ int h[NB];
    __shared__ int lastFlag;
    int b = blockIdx.x, t = threadIdx.x;
    for (int j = t; j < NB; j += 256) h[j] = 0;
    __syncthreads();
    const int EPB = NE / 256;  // 6250
    int e0 = b * EPB;
    for (int k = t; k < EPB; k += 256) atomicAdd(&h[ei[NE + e0 + k] >> BSH], 1);
    __syncthreads();
    for (int j = t; j < NB; j += 256) if (h[j]) atomicAdd(&cnt[j], h[j]);
    // ---- last-done block performs the scan + params ----
    if (t == 0) {
        __threadfence();
        int r = atomicAdd(done, 1);
        lastFlag = (r == (int)gridDim.x - 1);
    }
    __syncthreads();
    if (!lastFlag) return;
    // each thread owns 2 consecutive buckets (512 >= 391)
    int j0 = 2 * t;
    int c0 = 0, c1 = 0;
    if (j0 < NB)     c0 = atomicAdd(&cnt[j0], 0);      // device-scope load (skip stale L1)
    if (j0 + 1 < NB) c1 = atomicAdd(&cnt[j0 + 1], 0);
    int s = c0 + c1;
    __syncthreads();           // h[] reuse as scan buffer
    h[t] = s;
    __syncthreads();
    for (int o = 1; o < 256; o <<= 1) {
        int add = (t >= o) ? h[t - o] : 0;
        __syncthreads();
        h[t] += add;
        __syncthreads();
    }
    int e = h[t] - s;  // exclusive prefix over thread-pairs
    if (j0 < NB)     { bstart[j0] = e;     gcursor[j0 * GCS] = e; }
    e += c0;
    if (j0 + 1 < NB) { bstart[j0 + 1] = e; gcursor[(j0 + 1) * GCS] = e; }
    if (t == 0) bstart[NB] = NE;
    // ---- gate params (threads 0..31) ----
    if (t < HH) {
        int j = t;
        float az = 0.f, bz = 0.f, ah = 0.f, bh = 0.f;
        for (int k = 0; k < HH; ++k) {
            float lz = lzw[k * HH + j];
            float lh = lhw[k * HH + j];
            az = fmaf(czw[k], lz, az);
            bz = fmaf(czb[k], lz, bz);
            ah = fmaf(chw[k], lh, ah);
            bh = fmaf(chb[k], lh, bh);
        }
        // pre-scale by log2e so the hot loop uses raw v_exp_f32 (2^x)
        P[j]        = az * LOG2E;
        P[HH + j]   = (bz + lzb[j]) * LOG2E;
        P[2*HH + j] = 2.0f * LOG2E * ah;          // tanh(x) = f(2^(2x*log2e))
        P[3*HH + j] = 2.0f * LOG2E * (bh + lhb[j]);
    }
    if (t == 0) {
        float m = -1e30f;
        for (int q = 0; q < TT; ++q) m = fmaxf(m, att[q]);
        float ex[TT]; float ssum = 0.f;
        for (int q = 0; q < TT; ++q) { ex[q] = expf(att[q] - m); ssum += ex[q]; }
        for (int q = 0; q < TT; ++q) P[4*HH + q] = ex[q] / ssum;
    }
}

// Chunk-local counting sort: bin 4096 edges in LDS, reserve per-bucket global
// runs (1 atomic per non-empty bucket), stream out so each cache line is
// written by one wave in one burst. rec.y = raw ew (dinv folded downstream).
__global__ __launch_bounds__(512) void k_scatter(const int* __restrict__ ei,
                                                 const float* __restrict__ ew,
                                                 int* __restrict__ gcursor,
                                                 int2* __restrict__ rec) {
    __shared__ int2 cbuf[CHUNK];                 // 32 KB
    __shared__ unsigned short bkt[CHUNK];        // 8 KB
    __shared__ int sc[512];
    __shared__ int cnt[NB], off[NB], cur[NB], gb[NB];
    int t = threadIdx.x;
    int base = blockIdx.x * CHUNK;
    int m = min(CHUNK, NE - base);
    for (int j = t; j < NB; j += 512) { cnt[j] = 0; cur[j] = 0; }
    __syncthreads();
    int dsts[8], srcs[8]; float ews[8];
#pragma unroll
    for (int i = 0; i < 8; ++i) {
        int k = t + i * 512;
        if (k < m) {
            int e = base + k;
            dsts[i] = ei[NE + e]; srcs[i] = ei[e]; ews[i] = ew[e];
            atomicAdd(&cnt[dsts[i] >> BSH], 1);
        }
    }
    __syncthreads();
    int v = (t < NB) ? cnt[t] : 0;
    sc[t] = v;
    __syncthreads();
    for (int o = 1; o < 512; o <<= 1) {
        int add = (t >= o) ? sc[t - o] : 0;
        __syncthreads();
        sc[t] += add;
        __syncthreads();
    }
    if (t < NB) {
        off[t] = sc[t] - v;
        gb[t] = v ? atomicAdd(&gcursor[t * GCS], v) : 0;
    }
    __syncthreads();
#pragma unroll
    for (int i = 0; i < 8; ++i) {
        int k = t + i * 512;
        if (k < m) {
            int b = dsts[i] >> BSH;
            int p = off[b] + atomicAdd(&cur[b], 1);
            // src in bits 0..16 (100000 < 2^17), node-local dst (d&255) in 17..24
            cbuf[p] = make_int2(srcs[i] | ((dsts[i] & 255) << 17), __float_as_int(ews[i]));
            bkt[p] = (unsigned short)b;
        }
    }
    __syncthreads();
    for (int k = t; k < m; k += 512) {
        int b = bkt[k];
        rec[gb[b] + (k - off[b])] = cbuf[k];
    }
}

__device__ __forceinline__ u32 bfpack(float a, float b) {  // RNE bf16 pair
    u32 ua = __float_as_uint(a), ub = __float_as_uint(b);
    ua = (ua + 0x7FFFu + ((ua >> 16) & 1u)) >> 16;
    ub = (ub + 0x7FFFu + ((ub >> 16) & 1u)) >> 16;
    return ua | (ub << 16);
}

// One block per bucket: ONE streaming pass over the bucket's records builds
// per-node weighted degree via LDS float atomics -> dinv + bf16 xpb rows.
// This replaces k_sort entirely: no in-bucket counting sort, no 256-step
// scan, no 12.8MB rec rewrite — k_agg consumes records in arbitrary order.
__global__ __launch_bounds__(512) void k_deg(const int* __restrict__ bstart,
                                             const int2* __restrict__ rec,
                                             float* __restrict__ dinv,
                                             const float* __restrict__ x,
                                             u32* __restrict__ xpb) {
    __shared__ float wsum[256];
    int blk = blockIdx.x, t = threadIdx.x;
    int g0 = bstart[blk], g1 = bstart[blk + 1];
    if (t < 256) wsum[t] = 0.f;
    __syncthreads();
    for (int k = g0 + t; k < g1; k += 512) {
        int2 r = rec[k];
        atomicAdd(&wsum[(r.x >> 17) & 255], __int_as_float(r.y));
    }
    __syncthreads();
    if (t < 256) {
        int n = (blk << BSH) + t;
        if (n < NN) {
            float dv = rsqrtf(1.0f + wsum[t]);  // +1 = self loop
            dinv[n] = dv;
            const float4* xr = (const float4*)(x + (long)n * TT);
            float4 v0 = xr[0], v1 = xr[1], v2 = xr[2];
            uint4* xo = (uint4*)(xpb + ((long)n << 3));
            uint4 w0, w1;
            w0.x = bfpack(v0.x * dv, v0.y * dv);
            w0.y = bfpack(v0.z * dv, v0.w * dv);
            w0.z = bfpack(v1.x * dv, v1.y * dv);
            w0.w = bfpack(v1.z * dv, v1.w * dv);
            w1.x = bfpack(v2.x * dv, v2.y * dv);
            w1.y = bfpack(v2.z * dv, v2.w * dv);
            w1.z = 0u; w1.w = 0u;
            xo[0] = w0; xo[1] = w1;
        }
    }
}

#define BLO(w) __uint_as_float((w) << 16)
#define BHI(w) __uint_as_float((w) & 0xFFFF0000u)

// One block per bucket, 1024 threads (16 waves). Records in arbitrary order:
// per edge = 8B coalesced rec + one 32B L2-resident xpb gather + 12
// ds_add_f32 into acc[256][13] (odd 13-stride spreads random loc over all
// 32 banks). Every loop iteration is fully independent — no accumulator
// dependence chain, no per-lane degree imbalance (bucket sizes uniform
// 4096±64) — unlike the old per-node walk, which stayed ~35us invariant
// to VALU/occupancy/footprint because of its dependent 2-load chain.
// Epilogue: 4 threads/node x 8 channels, shfl_xor(1|2) combine.
__global__ __launch_bounds__(1024) void k_agg(const int* __restrict__ bstart,
                                              const int2* __restrict__ rec,
                                              const float* __restrict__ dinv,
                                              const u32* __restrict__ xpb,
                                              const float* __restrict__ P,
                                              const float* __restrict__ hw,
                                              const float* __restrict__ hb,
                                              float* __restrict__ out) {
    __shared__ float acc[256 * 13];              // 13.3 KB
    __shared__ float dvs[256];
    int blk = blockIdx.x, t = threadIdx.x;
    int g0 = bstart[blk], g1 = bstart[blk + 1];
    int nbase = blk << BSH;
    if (t < 256) {
        int n = nbase + t;
        dvs[t] = (n < NN) ? dinv[n] : 0.f;
    }
    for (int i = t; i < 256 * 13; i += 1024) acc[i] = 0.f;
    __syncthreads();
    for (int k = g0 + t; k < g1; k += 1024) {
        int2 r = rec[k];
        int loc = (r.x >> 17) & 255;
        float c = __int_as_float(r.y) * dvs[loc];   // ew * dinv[dst]; dinv[src] in xpb
        const uint4* xs = (const uint4*)(xpb + ((long)(r.x & 0x1FFFF) << 3));
        uint4 h0 = xs[0];                        // periods 0-7 (16B)
        uint2 h1 = *(const uint2*)(xs + 1);      // periods 8-11 (8B)
        float* A = acc + loc * 13;
        atomicAdd(A + 0,  c * BLO(h0.x)); atomicAdd(A + 1,  c * BHI(h0.x));
        atomicAdd(A + 2,  c * BLO(h0.y)); atomicAdd(A + 3,  c * BHI(h0.y));
        atomicAdd(A + 4,  c * BLO(h0.z)); atomicAdd(A + 5,  c * BHI(h0.z));
        atomicAdd(A + 6,  c * BLO(h0.w)); atomicAdd(A + 7,  c * BHI(h0.w));
        atomicAdd(A + 8,  c * BLO(h1.x)); atomicAdd(A + 9,  c * BHI(h1.x));
        atomicAdd(A + 10, c * BLO(h1.y)); atomicAdd(A + 11, c * BHI(h1.y));
    }
    __syncthreads();
    // --- epilogue: 4 threads per node, 8 hidden channels each ---
    int loc = t >> 2, quarter = t & 3;
    int n = nbase + loc;
    if (n >= NN) return;
    float di = dvs[loc];   // self term = dinv * (bf16 row)
    const uint4* xr = (const uint4*)(xpb + ((long)n << 3));
    uint4 h0 = xr[0];
    uint2 h1 = *(const uint2*)(xr + 1);
    const float* A = acc + loc * 13;
    float a[TT];
    a[0]  = A[0]  + di * BLO(h0.x); a[1]  = A[1]  + di * BHI(h0.x);
    a[2]  = A[2]  + di * BLO(h0.y); a[3]  = A[3]  + di * BHI(h0.y);
    a[4]  = A[4]  + di * BLO(h0.z); a[5]  = A[5]  + di * BHI(h0.z);
    a[6]  = A[6]  + di * BLO(h0.w); a[7]  = A[7]  + di * BHI(h0.w);
    a[8]  = A[8]  + di * BLO(h1.x); a[9]  = A[9]  + di * BHI(h1.x);
    a[10] = A[10] + di * BLO(h1.y); a[11] = A[11] + di * BHI(h1.y);
    float p[TT];
#pragma unroll
    for (int q = 0; q < TT; ++q) p[q] = P[4*HH + q];
    float o = 0.f;
#pragma unroll
    for (int jj = 0; jj < 8; ++jj) {
        int j = (jj << 2) | quarter;
        float Az = P[j], Bz = P[HH + j], Ah2 = P[2*HH + j], Bh2 = P[3*HH + j];
        float w = hw[j];
        float acc2 = 0.f;
#pragma unroll
        for (int q = 0; q < TT; ++q) {
            float xz = fmaf(a[q], Az, Bz);                   // log2-domain
            float xh = fminf(fmaf(a[q], Ah2, Bh2), 115.f);   // keep eh finite
            float ez = __builtin_amdgcn_exp2f(xz);  // e^orig_xz
            float eh = __builtin_amdgcn_exp2f(xh);  // e^(2*orig_xh)
            float den = (1.f + ez) * (eh + 1.f);
            float num = eh - 1.f;
            acc2 = fmaf(p[q] * num, __builtin_amdgcn_rcpf(den), acc2);
        }
        o = fmaf(fmaxf(acc2, 0.f), w, o);
    }
    o += __shfl_xor(o, 1);
    o += __shfl_xor(o, 2);
    if (quarter == 0) out[n] = o + hb[0];
}

extern "C" void kernel_launch(void* const* d_in, const int* in_sizes, int n_in,
                              void* d_out, int out_size, void* d_ws, size_t ws_size,
                              hipStream_t stream) {
    const float* x    = (const float*)d_in[0];
    const int*   ei   = (const int*)d_in[1];
    const float* ew   = (const float*)d_in[2];
    const float* att  = (const float*)d_in[3];
    const float* czw  = (const float*)d_in[4];
    const float* czb  = (const float*)d_in[5];
    const float* lzw  = (const float*)d_in[6];
    const float* lzb  = (const float*)d_in[7];
    // conv_r / lin_r (d_in[8..11]) are mathematically dead: H=0 -> H*R=0, Z*H=0.
    const float* chw  = (const float*)d_in[12];
    const float* chb  = (const float*)d_in[13];
    const float* lhw  = (const float*)d_in[14];
    const float* lhb  = (const float*)d_in[15];
    const float* hw   = (const float*)d_in[16];
    const float* hb   = (const float*)d_in[17];
    float* out = (float*)d_out;

    int*  ws32     = (int*)d_ws;
    int*  bstart   = ws32;                     // 392 (pad to 400)
    int*  cnt      = ws32 + 400;               // 391 (pad to 400)
    int*  done     = ws32 + 800;               // 1 (pad to 16)
    int*  gcursor  = ws32 + 816;               // NB*GCS = 6256
    float* dinv    = (float*)(ws32 + 107088);  // NN
    u32*  xpb      = (u32*)(ws32 + 207104);    // NN*8 u32, 32B rows (3.2MB)
    int2* rec      = (int2*)(ws32 + 1007104);  // NE int2
    float* P       = (float*)(ws32 + 4207104); // 144

    k_zero<<<1, 512, 0, stream>>>(ws32);
    k_pre<<<256, 256, 0, stream>>>(ei, cnt, done, bstart, gcursor,
                                   czw, czb, lzw, lzb, chw, chb, lhw, lhb, att, P);
    k_scatter<<<(NE + CHUNK - 1) / CHUNK, 512, 0, stream>>>(ei, ew, gcursor, rec);
    k_deg<<<NB, 512, 0, stream>>>(bstart, rec, dinv, x, xpb);
    k_agg<<<NB, 1024, 0, stream>>>(bstart, rec, dinv, xpb, P, hw, hb, out);
}

// Round 9
// 107.212 us; speedup vs baseline: 1.8633x; 1.8633x over previous
//
#include <hip/hip_runtime.h>

#define NN 100000
#define NE 1600000
#define TT 12
#define HH 32
#define NB 391          // coarse buckets of 256 nodes (node bucket = d >> 8)
#define BSH 8
#define GCS 16          // gcursor stride (ints) = one 64B line per cursor
#define CHUNK 4096      // edges per scatter block
#define SORTCAP 4800    // records per walk block (mean 4096, sigma 64 -> +11 sigma)
#define LOG2E 1.4426950408889634f

typedef unsigned int u32;

// ---------------- workspace layout (4-byte units), ~16.5 MB ----------------
// [0, 400)             : bstart[392]
// [400, 800)           : cnt[391]      (zeroed by k_zero)
// [800, 816)           : done flag     (zeroed by k_zero)
// [816, 7072)          : gcursor (x16 padded)
// [107104, 907104)     : xt (u32[NN][8]) 32B rows:
//                        [bf16x2 x0..x11 (6 u32)][dinv fp32 (slot6)][pad]
//                        x-part built in k_pre; dinv filled by k_deg
// [907104, 4107104)    : rec (int2[NE]) — bucket-grouped, NOT node-sorted
// [4107104, 4107248)   : P params: Az[32],Bz[32],Ah2[32],Bh2[32],probs[12]
// NOTE: ~41us __amd_rocclr_fillBufferAligned dispatches in rocprof are the
// harness's 256MiB workspace re-poison (reset phase) — NOT in the timed window.
// R8 lesson: >1 LDS atomic per edge is catastrophic (12/edge = 145us kernel);
// 1/edge (histogram/wsum) is fine. R2 lesson: global float atomics forbidden.

__global__ __launch_bounds__(512) void k_zero(int* __restrict__ ws32) {
    int t = threadIdx.x;
    if (t < 416) ws32[400 + t] = 0;   // cnt[391] + pad + done
}

__device__ __forceinline__ u32 bfpack(float a, float b) {  // RNE bf16 pair
    u32 ua = __float_as_uint(a), ub = __float_as_uint(b);
    ua = (ua + 0x7FFFu + ((ua >> 16) & 1u)) >> 16;
    ub = (ub + 0x7FFFu + ((ub >> 16) & 1u)) >> 16;
    return ua | (ub << 16);
}

// Bucket histogram + bf16 x-table build; LAST block (done counter) performs
// the bucket scan + gate-param folding. 512 blocks (was 256) to halve the
// per-block LDS-atomic histogram serial cost.
__global__ __launch_bounds__(256) void k_pre(const int* __restrict__ ei,
                                             const float* __restrict__ x,
                                             u32* __restrict__ xt,
                                             int* __restrict__ cnt,
                                             int* __restrict__ done,
                                             int* __restrict__ bstart,
                                             int* __restrict__ gcursor,
                                             const float* __restrict__ czw, const float* __restrict__ czb,
                                             const float* __restrict__ lzw, const float* __restrict__ lzb,
                                             const float* __restrict__ chw, const float* __restrict__ chb,
                                             const float* __restrict__ lhw, const float* __restrict__ lhb,
                                             const float* __restrict__ att, float* __restrict__ P) {
    __shared__ int h[NB];
    __shared__ int lastFlag;
    int b = blockIdx.x, t = threadIdx.x;
    for (int j = t; j < NB; j += 256) h[j] = 0;
    __syncthreads();
    const int EPB = NE / 512;  // 3125
    int e0 = b * EPB;
    for (int k = t; k < EPB; k += 256) atomicAdd(&h[ei[NE + e0 + k] >> BSH], 1);
    // x-table rows for this block's 196-node slice (contiguous -> coalesced)
    {
        int n = b * 196 + t;
        if (t < 196 && n < NN) {
            const float4* xr = (const float4*)(x + (long)n * TT);
            float4 v0 = xr[0], v1 = xr[1], v2 = xr[2];
            uint4* xo = (uint4*)(xt + ((long)n << 3));
            uint4 w0, w1;
            w0.x = bfpack(v0.x, v0.y); w0.y = bfpack(v0.z, v0.w);
            w0.z = bfpack(v1.x, v1.y); w0.w = bfpack(v1.z, v1.w);
            w1.x = bfpack(v2.x, v2.y); w1.y = bfpack(v2.z, v2.w);
            w1.z = 0u; w1.w = 0u;               // slot6 = dinv, filled by k_deg
            xo[0] = w0; xo[1] = w1;
        }
    }
    __syncthreads();
    for (int j = t; j < NB; j += 256) if (h[j]) atomicAdd(&cnt[j], h[j]);
    // ---- last-done block performs the scan + params ----
    if (t == 0) {
        __threadfence();
        int r = atomicAdd(done, 1);
        lastFlag = (r == (int)gridDim.x - 1);
    }
    __syncthreads();
    if (!lastFlag) return;
    int j0 = 2 * t;    // 2 consecutive buckets per thread (512 >= 391)
    int c0 = 0, c1 = 0;
    if (j0 < NB)     c0 = atomicAdd(&cnt[j0], 0);      // device-scope load
    if (j0 + 1 < NB) c1 = atomicAdd(&cnt[j0 + 1], 0);
    int s = c0 + c1;
    __syncthreads();           // h[] reuse as scan buffer
    h[t] = s;
    __syncthreads();
    for (int o = 1; o < 256; o <<= 1) {
        int add = (t >= o) ? h[t - o] : 0;
        __syncthreads();
        h[t] += add;
        __syncthreads();
    }
    int e = h[t] - s;  // exclusive prefix over thread-pairs
    if (j0 < NB)     { bstart[j0] = e;     gcursor[j0 * GCS] = e; }
    e += c0;
    if (j0 + 1 < NB) { bstart[j0 + 1] = e; gcursor[(j0 + 1) * GCS] = e; }
    if (t == 0) bstart[NB] = NE;
    // ---- gate params (threads 0..31) ----
    if (t < HH) {
        int j = t;
        float az = 0.f, bz = 0.f, ah = 0.f, bh = 0.f;
        for (int k = 0; k < HH; ++k) {
            float lz = lzw[k * HH + j];
            float lh = lhw[k * HH + j];
            az = fmaf(czw[k], lz, az);
            bz = fmaf(czb[k], lz, bz);
            ah = fmaf(chw[k], lh, ah);
            bh = fmaf(chb[k], lh, bh);
        }
        // pre-scale by log2e so the hot loop uses raw v_exp_f32 (2^x)
        P[j]        = az * LOG2E;
        P[HH + j]   = (bz + lzb[j]) * LOG2E;
        P[2*HH + j] = 2.0f * LOG2E * ah;          // tanh(x) = f(2^(2x*log2e))
        P[3*HH + j] = 2.0f * LOG2E * (bh + lhb[j]);
    }
    if (t == 0) {
        float m = -1e30f;
        for (int q = 0; q < TT; ++q) m = fmaxf(m, att[q]);
        float ex[TT]; float ssum = 0.f;
        for (int q = 0; q < TT; ++q) { ex[q] = expf(att[q] - m); ssum += ex[q]; }
        for (int q = 0; q < TT; ++q) P[4*HH + q] = ex[q] / ssum;
    }
}

// Chunk-local counting sort into bucket-grouped global runs. rec.y = raw ew.
__global__ __launch_bounds__(512) void k_scatter(const int* __restrict__ ei,
                                                 const float* __restrict__ ew,
                                                 int* __restrict__ gcursor,
                                                 int2* __restrict__ rec) {
    __shared__ int2 cbuf[CHUNK];                 // 32 KB
    __shared__ unsigned short bkt[CHUNK];        // 8 KB
    __shared__ int sc[512];
    __shared__ int cnt[NB], off[NB], cur[NB], gb[NB];
    int t = threadIdx.x;
    int base = blockIdx.x * CHUNK;
    int m = min(CHUNK, NE - base);
    for (int j = t; j < NB; j += 512) { cnt[j] = 0; cur[j] = 0; }
    __syncthreads();
    int dsts[8], srcs[8]; float ews[8];
#pragma unroll
    for (int i = 0; i < 8; ++i) {
        int k = t + i * 512;
        if (k < m) {
            int e = base + k;
            dsts[i] = ei[NE + e]; srcs[i] = ei[e]; ews[i] = ew[e];
            atomicAdd(&cnt[dsts[i] >> BSH], 1);
        }
    }
    __syncthreads();
    int v = (t < NB) ? cnt[t] : 0;
    sc[t] = v;
    __syncthreads();
    for (int o = 1; o < 512; o <<= 1) {
        int add = (t >= o) ? sc[t - o] : 0;
        __syncthreads();
        sc[t] += add;
        __syncthreads();
    }
    if (t < NB) {
        off[t] = sc[t] - v;
        gb[t] = v ? atomicAdd(&gcursor[t * GCS], v) : 0;
    }
    __syncthreads();
#pragma unroll
    for (int i = 0; i < 8; ++i) {
        int k = t + i * 512;
        if (k < m) {
            int b = dsts[i] >> BSH;
            int p = off[b] + atomicAdd(&cur[b], 1);
            // src in bits 0..16 (100000 < 2^17), node-local dst (d&255) in 17..24
            cbuf[p] = make_int2(srcs[i] | ((dsts[i] & 255) << 17), __float_as_int(ews[i]));
            bkt[p] = (unsigned short)b;
        }
    }
    __syncthreads();
    for (int k = t; k < m; k += 512) {
        int b = bkt[k];
        rec[gb[b] + (k - off[b])] = cbuf[k];
    }
}

// Per-bucket weighted degree (1 LDS atomic/edge) -> dinv written into xt slot 6.
__global__ __launch_bounds__(512) void k_deg(const int* __restrict__ bstart,
                                             const int2* __restrict__ rec,
                                             u32* __restrict__ xt) {
    __shared__ float wsum[256];
    int blk = blockIdx.x, t = threadIdx.x;
    int g0 = bstart[blk], g1 = bstart[blk + 1];
    if (t < 256) wsum[t] = 0.f;
    __syncthreads();
    for (int k = g0 + t; k < g1; k += 512) {
        int2 r = rec[k];
        atomicAdd(&wsum[(r.x >> 17) & 255], __int_as_float(r.y));
    }
    __syncthreads();
    if (t < 256) {
        int n = (blk << BSH) + t;
        if (n < NN)
            xt[((long)n << 3) + 6] = __float_as_uint(rsqrtf(1.0f + wsum[t]));
    }
}

#define BLO(w) __uint_as_float((w) << 16)
#define BHI(w) __uint_as_float((w) & 0xFFFF0000u)

// One block per bucket, 1024 threads. Single global read of the bucket's
// records -> LDS buf + histogram; 256-scan; perm[] built with 1 LDS
// atomic/edge (R8 lesson); then 4 lanes/node walk their perm segment,
// gathering ONE 32B xt row per edge (bf16 x + dinv_src in slot 6 — one
// line supplies both). Replaces k_sort's 12.8MB sorted-rec global write +
// k_fused's 12.8MB re-read + one launch. LDS ~51KB, 2 blocks/CU.
__global__ __launch_bounds__(1024) void k_walk(const int* __restrict__ bstart,
                                               const int2* __restrict__ rec,
                                               const u32* __restrict__ xt,
                                               const float* __restrict__ P,
                                               const float* __restrict__ hw,
                                               const float* __restrict__ hb,
                                               float* __restrict__ out) {
    __shared__ int2 buf[SORTCAP];                // 37.5 KB
    __shared__ unsigned short perm[SORTCAP];     // 9.4 KB
    __shared__ int cnt[256], cur[256], sc[256];
    __shared__ float dvs[256];
    int blk = blockIdx.x, t = threadIdx.x;
    int g0 = bstart[blk], g1 = bstart[blk + 1];
    int m = min(g1 - g0, SORTCAP);
    int nbase = blk << BSH;
    if (t < 256) {
        cnt[t] = 0;
        int n = nbase + t;
        dvs[t] = (n < NN) ? __uint_as_float(xt[((long)n << 3) + 6]) : 0.f;
    }
    __syncthreads();
    for (int k = t; k < m; k += 1024) {
        int2 r = rec[g0 + k];
        buf[k] = r;
        atomicAdd(&cnt[(r.x >> 17) & 255], 1);
    }
    __syncthreads();
    int v = (t < 256) ? cnt[t] : 0;
    if (t < 256) sc[t] = v;
    __syncthreads();
    for (int o = 1; o < 256; o <<= 1) {
        int add = (t < 256 && t >= o) ? sc[t - o] : 0;
        __syncthreads();
        if (t < 256) sc[t] += add;
        __syncthreads();
    }
    if (t < 256) cur[t] = sc[t] - v;   // exclusive prefix = segment start
    __syncthreads();
    for (int k = t; k < m; k += 1024) {
        int loc = (buf[k].x >> 17) & 255;
        int pos = atomicAdd(&cur[loc], 1);
        perm[pos] = (unsigned short)k;
    }
    __syncthreads();
    // ---- walk: 4 lanes per node ----
    int loc = t >> 2, quarter = t & 3;
    int n = nbase + loc;
    float a[TT];
#pragma unroll
    for (int q = 0; q < TT; ++q) a[q] = 0.f;
    if (n < NN) {
        float di = dvs[loc];
        int s1 = cur[loc];            // after perm-build: segment end
        int s0 = s1 - cnt[loc];
        if (quarter == 0) {           // self loop: c = dinv^2, own row
            const uint4* xs = (const uint4*)(xt + ((long)n << 3));
            uint4 h0 = xs[0], h1 = xs[1];
            float c = di * di;
            a[0]  = c * BLO(h0.x); a[1]  = c * BHI(h0.x);
            a[2]  = c * BLO(h0.y); a[3]  = c * BHI(h0.y);
            a[4]  = c * BLO(h0.z); a[5]  = c * BHI(h0.z);
            a[6]  = c * BLO(h0.w); a[7]  = c * BHI(h0.w);
            a[8]  = c * BLO(h1.x); a[9]  = c * BHI(h1.x);
            a[10] = c * BLO(h1.y); a[11] = c * BHI(h1.y);
        }
        for (int i = s0 + quarter; i < s1; i += 4) {
            int2 r = buf[perm[i]];
            const uint4* xs = (const uint4*)(xt + ((long)(r.x & 0x1FFFF) << 3));
            uint4 h0 = xs[0], h1 = xs[1];   // one 32B line: x bf16 + dinv_src
            float c = __int_as_float(r.y) * __uint_as_float(h1.z) * di;
            a[0]  = fmaf(c, BLO(h0.x), a[0]);  a[1]  = fmaf(c, BHI(h0.x), a[1]);
            a[2]  = fmaf(c, BLO(h0.y), a[2]);  a[3]  = fmaf(c, BHI(h0.y), a[3]);
            a[4]  = fmaf(c, BLO(h0.z), a[4]);  a[5]  = fmaf(c, BHI(h0.z), a[5]);
            a[6]  = fmaf(c, BLO(h0.w), a[6]);  a[7]  = fmaf(c, BHI(h0.w), a[7]);
            a[8]  = fmaf(c, BLO(h1.x), a[8]);  a[9]  = fmaf(c, BHI(h1.x), a[9]);
            a[10] = fmaf(c, BLO(h1.y), a[10]); a[11] = fmaf(c, BHI(h1.y), a[11]);
        }
    }
    // combine the 4 lanes of this node
#pragma unroll
    for (int q = 0; q < TT; ++q) {
        float vv = a[q];
        vv += __shfl_xor(vv, 1);
        vv += __shfl_xor(vv, 2);
        a[q] = vv;
    }
    if (n >= NN) return;
    // --- epilogue: gates + attention + head, 8 hidden channels per lane ---
    float p[TT];
#pragma unroll
    for (int q = 0; q < TT; ++q) p[q] = P[4*HH + q];
    float o = 0.f;
#pragma unroll
    for (int jj = 0; jj < 8; ++jj) {
        int j = (jj << 2) | quarter;
        float Az = P[j], Bz = P[HH + j], Ah2 = P[2*HH + j], Bh2 = P[3*HH + j];
        float w = hw[j];
        float acc = 0.f;
#pragma unroll
        for (int q = 0; q < TT; ++q) {
            float xz = fmaf(a[q], Az, Bz);                   // log2-domain
            float xh = fminf(fmaf(a[q], Ah2, Bh2), 115.f);   // keep eh finite
            float ez = __builtin_amdgcn_exp2f(xz);  // e^orig_xz
            float eh = __builtin_amdgcn_exp2f(xh);  // e^(2*orig_xh)
            float den = (1.f + ez) * (eh + 1.f);
            float num = eh - 1.f;
            acc = fmaf(p[q] * num, __builtin_amdgcn_rcpf(den), acc);
        }
        o = fmaf(fmaxf(acc, 0.f), w, o);
    }
    o += __shfl_xor(o, 1);
    o += __shfl_xor(o, 2);
    if (quarter == 0) out[n] = o + hb[0];
}

extern "C" void kernel_launch(void* const* d_in, const int* in_sizes, int n_in,
                              void* d_out, int out_size, void* d_ws, size_t ws_size,
                              hipStream_t stream) {
    const float* x    = (const float*)d_in[0];
    const int*   ei   = (const int*)d_in[1];
    const float* ew   = (const float*)d_in[2];
    const float* att  = (const float*)d_in[3];
    const float* czw  = (const float*)d_in[4];
    const float* czb  = (const float*)d_in[5];
    const float* lzw  = (const float*)d_in[6];
    const float* lzb  = (const float*)d_in[7];
    // conv_r / lin_r (d_in[8..11]) are mathematically dead: H=0 -> H*R=0, Z*H=0.
    const float* chw  = (const float*)d_in[12];
    const float* chb  = (const float*)d_in[13];
    const float* lhw  = (const float*)d_in[14];
    const float* lhb  = (const float*)d_in[15];
    const float* hw   = (const float*)d_in[16];
    const float* hb   = (const float*)d_in[17];
    float* out = (float*)d_out;

    int*  ws32     = (int*)d_ws;
    int*  bstart   = ws32;                     // 392 (pad to 400)
    int*  cnt      = ws32 + 400;               // 391 (pad to 400)
    int*  done     = ws32 + 800;               // 1 (pad to 16)
    int*  gcursor  = ws32 + 816;               // NB*GCS = 6256
    u32*  xt       = (u32*)(ws32 + 107104);    // NN*8 u32, 32B rows (3.2MB)
    int2* rec      = (int2*)(ws32 + 907104);   // NE int2
    float* P       = (float*)(ws32 + 4107104); // 144

    k_zero<<<1, 512, 0, stream>>>(ws32);
    k_pre<<<512, 256, 0, stream>>>(ei, x, xt, cnt, done, bstart, gcursor,
                                   czw, czb, lzw, lzb, chw, chb, lhw, lhb, att, P);
    k_scatter<<<(NE + CHUNK - 1) / CHUNK, 512, 0, stream>>>(ei, ew, gcursor, rec);
    k_deg<<<NB, 512, 0, stream>>>(bstart, rec, xt);
    k_walk<<<NB, 1024, 0, stream>>>(bstart, rec, xt, P, hw, hb, out);
}

// Round 10
// 77.707 us; speedup vs baseline: 2.5708x; 1.3797x over previous
//
#include <hip/hip_runtime.h>

#define NN 100000
#define NE 1600000
#define TT 12
#define HH 32
#define NB 391          // coarse buckets of 256 nodes (node bucket = d >> 8)
#define NCH 391         // scatter chunks = ceil(NE/CHUNK) (== NB by coincidence)
#define BSH 8
#define CHUNK 4096      // edges per scatter block
#define SORTCAP 4800    // per-bucket capacity (mean 4096, sigma 64 -> +11 sigma)
#define LOG2E 1.4426950408889634f

typedef unsigned int u32;

// ---------------- workspace layout (4-byte units), ~32.4 MB ----------------
// [0, 153280)          : offT (int[NCH][392]): per-chunk bucket-run offsets,
//                        entry 391 = chunk size sentinel
// [153280, 253296)     : nodebase[100001] (pad to 253312)
// [253312, 253712)     : bend[391]  (bucket end in rec2)
// [253712, 353712)     : dinv (float[NN])
// [353712, 1153712)    : xpb (u32[NN][8]) bf16x2-packed dinv[n]*x[n], 32B rows
// [1153712, 4353712)   : rec (int2[NE])   — chunk-ordered (bucket-runs in chunk)
// [4353712, 8107312)   : rec2 (int2[NB*4800]) — node-sorted, fixed bucket slots
// [8107312, 8107456)   : P params: Az[32],Bz[32],Ah2[32],Bh2[32],probs[12]
// No global counters -> NOTHING needs zeroing, no global atomics anywhere.
// Session lessons: R2 global float atomics forbidden (uncached 32B writes);
// R8 >2 LDS atomics/edge forbidden; R9 heavy work on 391-block grids loses
// ~40% of the chip to block imbalance (keep coarse grids cheap).
// The ~41us __amd_rocclr_fillBufferAligned dispatches in rocprof are the
// harness's 256MiB workspace re-poison (reset phase) — NOT in the timed window.

// Gate-parameter folding (tiny). P pre-scaled by log2e -> raw v_exp_f32 hot loop.
__global__ void k_params(const float* __restrict__ czw, const float* __restrict__ czb,
                         const float* __restrict__ lzw, const float* __restrict__ lzb,
                         const float* __restrict__ chw, const float* __restrict__ chb,
                         const float* __restrict__ lhw, const float* __restrict__ lhb,
                         const float* __restrict__ att, float* __restrict__ P) {
    int j = threadIdx.x;
    if (j < HH) {
        float az = 0.f, bz = 0.f, ah = 0.f, bh = 0.f;
        for (int k = 0; k < HH; ++k) {
            float lz = lzw[k * HH + j];
            float lh = lhw[k * HH + j];
            az = fmaf(czw[k], lz, az);
            bz = fmaf(czb[k], lz, bz);
            ah = fmaf(chw[k], lh, ah);
            bh = fmaf(chb[k], lh, bh);
        }
        P[j]        = az * LOG2E;
        P[HH + j]   = (bz + lzb[j]) * LOG2E;
        P[2*HH + j] = 2.0f * LOG2E * ah;          // tanh(x) = f(2^(2x*log2e))
        P[3*HH + j] = 2.0f * LOG2E * (bh + lhb[j]);
    }
    if (threadIdx.x == 0) {
        float m = -1e30f;
        for (int q = 0; q < TT; ++q) m = fmaxf(m, att[q]);
        float ex[TT]; float s = 0.f;
        for (int q = 0; q < TT; ++q) { ex[q] = expf(att[q] - m); s += ex[q]; }
        for (int q = 0; q < TT; ++q) P[4*HH + q] = ex[q] / s;
    }
}

// Pass 1 (no prerequisites): chunk-local counting sort by bucket; chunk is
// written back COALESCED at its own base (bucket-runs in bucket order inside
// the chunk); per-chunk run offsets go to offT. No global scan, no global
// atomics, no gcursor — fixed-capacity bucket slots make them unnecessary.
__global__ __launch_bounds__(512) void k_scatter(const int* __restrict__ ei,
                                                 const float* __restrict__ ew,
                                                 int2* __restrict__ rec,
                                                 int* __restrict__ offT) {
    __shared__ int2 cbuf[CHUNK];                 // 32 KB
    __shared__ int sc[512];
    __shared__ int cnt[NB], off[NB], cur[NB];
    int t = threadIdx.x;
    int base = blockIdx.x * CHUNK;
    int m = min(CHUNK, NE - base);
    for (int j = t; j < NB; j += 512) { cnt[j] = 0; cur[j] = 0; }
    __syncthreads();
    int dsts[8], srcs[8]; float ews[8];
#pragma unroll
    for (int i = 0; i < 8; ++i) {
        int k = t + i * 512;
        if (k < m) {
            int e = base + k;
            dsts[i] = ei[NE + e]; srcs[i] = ei[e]; ews[i] = ew[e];
            atomicAdd(&cnt[dsts[i] >> BSH], 1);
        }
    }
    __syncthreads();
    int v = (t < NB) ? cnt[t] : 0;
    sc[t] = v;
    __syncthreads();
    for (int o = 1; o < 512; o <<= 1) {
        int add = (t >= o) ? sc[t - o] : 0;
        __syncthreads();
        sc[t] += add;
        __syncthreads();
    }
    if (t < NB) {
        int e = sc[t] - v;
        off[t] = e;
        offT[blockIdx.x * 392 + t] = e;
    }
    if (t == 0) offT[blockIdx.x * 392 + NB] = m;   // sentinel = chunk size
    __syncthreads();
#pragma unroll
    for (int i = 0; i < 8; ++i) {
        int k = t + i * 512;
        if (k < m) {
            int b = dsts[i] >> BSH;
            int p = off[b] + atomicAdd(&cur[b], 1);
            // src in bits 0..16 (100000 < 2^17), node-local dst (d&255) in 17..24
            cbuf[p] = make_int2(srcs[i] | ((dsts[i] & 255) << 17), __float_as_int(ews[i]));
        }
    }
    __syncthreads();
    for (int k = t; k < m; k += 512) rec[base + k] = cbuf[k];   // coalesced
}

__device__ __forceinline__ u32 bfpack(float a, float b) {  // RNE bf16 pair
    u32 ua = __float_as_uint(a), ub = __float_as_uint(b);
    ua = (ua + 0x7FFFu + ((ua >> 16) & 1u)) >> 16;
    ub = (ub + 0x7FFFu + ((ub >> 16) & 1u)) >> 16;
    return ua | (ub << 16);
}

// Pass 2: one block per bucket. Gathers the bucket's ~4096 records from 391
// short chunk-runs via offT (thread c copies run c: ~10.5 contiguous int2),
// then exactly the R7 k_sort body: histogram+wsum (2 LDS atomics/record,
// within budget), scan, dinv + bf16 xpb row build, sorted rewrite into the
// bucket's fixed rec2 slot [b*4800, b*4800+m).
__global__ __launch_bounds__(512) void k_sort(const int2* __restrict__ rec,
                                              const int* __restrict__ offT,
                                              int2* __restrict__ rec2,
                                              int* __restrict__ nodebase,
                                              int* __restrict__ bend,
                                              float* __restrict__ dinv,
                                              const float* __restrict__ x,
                                              u32* __restrict__ xpb) {
    __shared__ int2 buf[SORTCAP];                // 37.5 KB
    __shared__ int sc[512];
    __shared__ int cnt[256], cur[256];
    __shared__ float wsum[256], dvs[256];
    int b = blockIdx.x, t = threadIdx.x;
    // ---- run lengths + scan -> destination offsets in buf ----
    int o0 = 0, len = 0;
    if (t < NCH) {
        o0 = offT[t * 392 + b];
        len = offT[t * 392 + b + 1] - o0;
    }
    sc[t] = len;
    __syncthreads();
    for (int o = 1; o < 512; o <<= 1) {
        int add = (t >= o) ? sc[t - o] : 0;
        __syncthreads();
        sc[t] += add;
        __syncthreads();
    }
    int rdst = sc[t] - len;
    int m = min(sc[511], SORTCAP);
    if (t < 256) { cnt[t] = 0; wsum[t] = 0.f; }
    __syncthreads();
    // ---- ragged gather + histogram + wsum ----
    for (int j = 0; j < len; ++j) {
        int d = rdst + j;
        if (d >= SORTCAP) break;
        int2 r = rec[t * CHUNK + o0 + j];
        buf[d] = r;
        int loc = (r.x >> 17) & 255;
        atomicAdd(&cnt[loc], 1);
        atomicAdd(&wsum[loc], __int_as_float(r.y));
    }
    __syncthreads();
    // ---- per-node scan, dinv, nodebase, xpb row ----
    int v = (t < 256) ? cnt[t] : 0;
    sc[t] = v;
    __syncthreads();
    for (int o = 1; o < 256; o <<= 1) {
        int add = (t >= o) ? sc[t - o] : 0;
        __syncthreads();
        sc[t] += add;
        __syncthreads();
    }
    if (t < 256) {
        int e = sc[t] - v;  // exclusive prefix
        cur[t] = e;
        float dv = rsqrtf(1.0f + wsum[t]);  // +1 = self loop
        dvs[t] = dv;
        int n = (b << BSH) + t;
        if (n < NN) {
            dinv[n] = dv;
            nodebase[n] = b * SORTCAP + e;
            const float4* xr = (const float4*)(x + (long)n * TT);
            float4 v0 = xr[0], v1 = xr[1], v2 = xr[2];
            uint4* xo = (uint4*)(xpb + ((long)n << 3));
            uint4 w0, w1;
            w0.x = bfpack(v0.x * dv, v0.y * dv);
            w0.y = bfpack(v0.z * dv, v0.w * dv);
            w0.z = bfpack(v1.x * dv, v1.y * dv);
            w0.w = bfpack(v1.z * dv, v1.w * dv);
            w1.x = bfpack(v2.x * dv, v2.y * dv);
            w1.y = bfpack(v2.z * dv, v2.w * dv);
            w1.z = 0u; w1.w = 0u;
            xo[0] = w0; xo[1] = w1;
        }
    }
    if (t == 0) {
        bend[b] = b * SORTCAP + m;
        if (b == NB - 1) nodebase[NN] = b * SORTCAP + m;
    }
    __syncthreads();
    // ---- sorted rewrite ----
    for (int k = t; k < m; k += 512) {
        int2 r = buf[k];
        int loc = (r.x >> 17) & 255;
        int p = atomicAdd(&cur[loc], 1);
        float w2 = __int_as_float(r.y) * dvs[loc];  // fold dinv[dst] into weight
        rec2[b * SORTCAP + p] = make_int2(r.x & 0x1FFFF, __float_as_int(w2));
    }
}

#define BLO(w) __uint_as_float((w) << 16)
#define BHI(w) __uint_as_float((w) & 0xFFFF0000u)

// R7's proven gather kernel (best measured config): 8 lanes/node, each lane
// walks every-8th record (coalesced rec2), one 32B bf16 row per edge, 3-level
// shfl_xor reduce, exp2-domain epilogue. Only change: bucket-end boundary via
// bend[] for local-255 nodes (fixed-capacity bucket slots leave gaps in rec2).
__global__ __launch_bounds__(512) void k_fused(const int* __restrict__ nodebase,
                                               const int* __restrict__ bend,
                                               const int2* __restrict__ rec2,
                                               const float* __restrict__ dinv,
                                               const u32* __restrict__ xpb,
                                               const float* __restrict__ P,
                                               const float* __restrict__ hw,
                                               const float* __restrict__ hb,
                                               float* __restrict__ out) {
    int g = blockIdx.x * 512 + threadIdx.x;
    int n = g >> 3, sub = g & 7;
    if (n >= NN) return;
    float a[TT];
#pragma unroll
    for (int q = 0; q < TT; ++q) a[q] = 0.f;
    if (sub == 0) {
        float di = dinv[n];   // self term = dinv * (bf16 row)
        const uint4* xr = (const uint4*)(xpb + ((long)n << 3));
        uint4 h0 = xr[0];
        uint2 h1 = *(const uint2*)(xr + 1);
        a[0]  = di * BLO(h0.x); a[1]  = di * BHI(h0.x);
        a[2]  = di * BLO(h0.y); a[3]  = di * BHI(h0.y);
        a[4]  = di * BLO(h0.z); a[5]  = di * BHI(h0.z);
        a[6]  = di * BLO(h0.w); a[7]  = di * BHI(h0.w);
        a[8]  = di * BLO(h1.x); a[9]  = di * BHI(h1.x);
        a[10] = di * BLO(h1.y); a[11] = di * BHI(h1.y);
    }
    int k0 = nodebase[n];
    int k1 = ((n & 255) == 255) ? bend[n >> 8] : nodebase[n + 1];
    for (int k = k0 + sub; k < k1; k += 8) {
        int2 r = rec2[k];
        float c = __int_as_float(r.y);  // = ew * dinv[dst]; dinv[src] in xpb
        const uint4* xs = (const uint4*)(xpb + ((long)r.x << 3));
        uint4 h0 = xs[0];                       // periods 0-7 (16B)
        uint2 h1 = *(const uint2*)(xs + 1);     // periods 8-11 (8B)
        a[0]  = fmaf(c, BLO(h0.x), a[0]);  a[1]  = fmaf(c, BHI(h0.x), a[1]);
        a[2]  = fmaf(c, BLO(h0.y), a[2]);  a[3]  = fmaf(c, BHI(h0.y), a[3]);
        a[4]  = fmaf(c, BLO(h0.z), a[4]);  a[5]  = fmaf(c, BHI(h0.z), a[5]);
        a[6]  = fmaf(c, BLO(h0.w), a[6]);  a[7]  = fmaf(c, BHI(h0.w), a[7]);
        a[8]  = fmaf(c, BLO(h1.x), a[8]);  a[9]  = fmaf(c, BHI(h1.x), a[9]);
        a[10] = fmaf(c, BLO(h1.y), a[10]); a[11] = fmaf(c, BHI(h1.y), a[11]);
    }
    // tree-reduce the 12 accumulators across the 8 lanes of this node
#pragma unroll
    for (int q = 0; q < TT; ++q) {
        float v = a[q];
        v += __shfl_xor(v, 1);
        v += __shfl_xor(v, 2);
        v += __shfl_xor(v, 4);
        a[q] = v;
    }
    // --- epilogue: gates + attention + head, 4 hidden channels per lane ---
    float p[TT];
#pragma unroll
    for (int q = 0; q < TT; ++q) p[q] = P[4*HH + q];
    float o = 0.f;
#pragma unroll
    for (int jj = 0; jj < 4; ++jj) {
        int j = (jj << 3) + sub;
        float Az = P[j], Bz = P[HH + j], Ah2 = P[2*HH + j], Bh2 = P[3*HH + j];
        float w = hw[j];
        float acc = 0.f;
#pragma unroll
        for (int q = 0; q < TT; ++q) {
            float xz = fmaf(a[q], Az, Bz);                   // log2-domain
            float xh = fminf(fmaf(a[q], Ah2, Bh2), 115.f);   // keep eh finite
            float ez = __builtin_amdgcn_exp2f(xz);  // e^orig_xz
            float eh = __builtin_amdgcn_exp2f(xh);  // e^(2*orig_xh)
            float den = (1.f + ez) * (eh + 1.f);
            float num = eh - 1.f;
            acc = fmaf(p[q] * num, __builtin_amdgcn_rcpf(den), acc);
        }
        o = fmaf(fmaxf(acc, 0.f), w, o);
    }
    o += __shfl_xor(o, 1);
    o += __shfl_xor(o, 2);
    o += __shfl_xor(o, 4);
    if (sub == 0) out[n] = o + hb[0];
}

extern "C" void kernel_launch(void* const* d_in, const int* in_sizes, int n_in,
                              void* d_out, int out_size, void* d_ws, size_t ws_size,
                              hipStream_t stream) {
    const float* x    = (const float*)d_in[0];
    const int*   ei   = (const int*)d_in[1];
    const float* ew   = (const float*)d_in[2];
    const float* att  = (const float*)d_in[3];
    const float* czw  = (const float*)d_in[4];
    const float* czb  = (const float*)d_in[5];
    const float* lzw  = (const float*)d_in[6];
    const float* lzb  = (const float*)d_in[7];
    // conv_r / lin_r (d_in[8..11]) are mathematically dead: H=0 -> H*R=0, Z*H=0.
    const float* chw  = (const float*)d_in[12];
    const float* chb  = (const float*)d_in[13];
    const float* lhw  = (const float*)d_in[14];
    const float* lhb  = (const float*)d_in[15];
    const float* hw   = (const float*)d_in[16];
    const float* hb   = (const float*)d_in[17];
    float* out = (float*)d_out;

    int*  ws32     = (int*)d_ws;
    int*  offT     = ws32;                     // NCH*392 = 153272 (pad 153280)
    int*  nodebase = ws32 + 153280;            // 100001 (pad to 253312)
    int*  bend     = ws32 + 253312;            // 391 (pad to 253712)
    float* dinv    = (float*)(ws32 + 253712);  // NN
    u32*  xpb      = (u32*)(ws32 + 353712);    // NN*8 u32, 32B rows (3.2MB)
    int2* rec      = (int2*)(ws32 + 1153712);  // NE int2 (chunk-ordered)
    int2* rec2     = (int2*)(ws32 + 4353712);  // NB*4800 int2 (node-sorted)
    float* P       = (float*)(ws32 + 8107312); // 144

    k_params<<<1, 64, 0, stream>>>(czw, czb, lzw, lzb, chw, chb, lhw, lhb, att, P);
    k_scatter<<<NCH, 512, 0, stream>>>(ei, ew, rec, offT);
    k_sort<<<NB, 512, 0, stream>>>(rec, offT, rec2, nodebase, bend, dinv, x, xpb);
    k_fused<<<(NN * 8 + 511) / 512, 512, 0, stream>>>(nodebase, bend, rec2, dinv, xpb,
                                                      P, hw, hb, out);
}

// Round 11
// 71.324 us; speedup vs baseline: 2.8009x; 1.0895x over previous
//
#include <hip/hip_runtime.h>

#define NN 100000
#define NE 1600000
#define TT 12
#define HH 32
#define NB 391          // coarse buckets of 256 nodes (node bucket = d >> 8)
#define NCH 391         // scatter chunks = ceil(NE/CHUNK) (== NB by coincidence)
#define BSH 8
#define CHUNK 4096      // edges per scatter block
#define SORTCAP 4800    // per-bucket capacity (mean 4096, sigma 64 -> +11 sigma)
#define LOG2E 1.4426950408889634f

typedef unsigned int u32;

// ---------------- workspace layout (4-byte units), ~32.4 MB ----------------
// [0, 153280)          : offT (int[NCH][392]): per-chunk bucket-run offsets,
//                        entry 391 = chunk size sentinel
// [153280, 253296)     : nodebase[100001] (pad to 253312)
// [253312, 253712)     : bend[391]  (bucket end in rec2)
// [253712, 353712)     : dinv (float[NN])
// [353712, 1153712)    : xpb (u32[NN][8]) bf16x2-packed dinv[n]*x[n], 32B rows
// [1153712, 4353712)   : rec (int2[NE])   — chunk-ordered (bucket-runs in chunk)
// [4353712, 8107312)   : rec2 (int2[NB*4800]) — node-sorted, fixed bucket slots
// [8107312, 8107456)   : P params: Az[32],Bz[32],Ah2[32],Bh2[32],probs[12]
// No global counters -> NOTHING needs zeroing, no global atomics anywhere.
// Session lessons: R2 global float atomics forbidden (uncached 32B writes);
// R8 >2 LDS atomics/edge forbidden; R9 heavy work on 391-block grids loses
// ~40% of the chip to block imbalance; R10 scan-free fixed-slot layout won -19us.
// The ~41us __amd_rocclr_fillBufferAligned dispatches in rocprof are the
// harness's 256MiB workspace re-poison (reset phase) — NOT in the timed window.

// Pass 1 (no prerequisites): chunk-local counting sort by bucket; chunk is
// written back COALESCED at its own base; per-chunk run offsets go to offT.
// Grid NCH+1: the extra block (blockIdx == NCH) folds the gate params
// (launch-count reduction; params are independent of scatter).
__global__ __launch_bounds__(512) void k_scatter(const int* __restrict__ ei,
                                                 const float* __restrict__ ew,
                                                 int2* __restrict__ rec,
                                                 int* __restrict__ offT,
                                                 const float* __restrict__ czw, const float* __restrict__ czb,
                                                 const float* __restrict__ lzw, const float* __restrict__ lzb,
                                                 const float* __restrict__ chw, const float* __restrict__ chb,
                                                 const float* __restrict__ lhw, const float* __restrict__ lhb,
                                                 const float* __restrict__ att, float* __restrict__ P) {
    int t = threadIdx.x;
    if (blockIdx.x == NCH) {   // ---- gate-param block ----
        if (t < HH) {
            int j = t;
            float az = 0.f, bz = 0.f, ah = 0.f, bh = 0.f;
            for (int k = 0; k < HH; ++k) {
                float lz = lzw[k * HH + j];
                float lh = lhw[k * HH + j];
                az = fmaf(czw[k], lz, az);
                bz = fmaf(czb[k], lz, bz);
                ah = fmaf(chw[k], lh, ah);
                bh = fmaf(chb[k], lh, bh);
            }
            // pre-scale by log2e so the hot loop uses raw v_exp_f32 (2^x)
            P[j]        = az * LOG2E;
            P[HH + j]   = (bz + lzb[j]) * LOG2E;
            P[2*HH + j] = 2.0f * LOG2E * ah;          // tanh(x) = f(2^(2x*log2e))
            P[3*HH + j] = 2.0f * LOG2E * (bh + lhb[j]);
        }
        if (t == 0) {
            float m = -1e30f;
            for (int q = 0; q < TT; ++q) m = fmaxf(m, att[q]);
            float ex[TT]; float s = 0.f;
            for (int q = 0; q < TT; ++q) { ex[q] = expf(att[q] - m); s += ex[q]; }
            for (int q = 0; q < TT; ++q) P[4*HH + q] = ex[q] / s;
        }
        return;
    }
    __shared__ int2 cbuf[CHUNK];                 // 32 KB
    __shared__ int sc[512];
    __shared__ int cnt[NB], off[NB], cur[NB];
    int base = blockIdx.x * CHUNK;
    int m = min(CHUNK, NE - base);
    for (int j = t; j < NB; j += 512) { cnt[j] = 0; cur[j] = 0; }
    __syncthreads();
    int dsts[8], srcs[8]; float ews[8];
#pragma unroll
    for (int i = 0; i < 8; ++i) {
        int k = t + i * 512;
        if (k < m) {
            int e = base + k;
            dsts[i] = ei[NE + e]; srcs[i] = ei[e]; ews[i] = ew[e];
            atomicAdd(&cnt[dsts[i] >> BSH], 1);
        }
    }
    __syncthreads();
    int v = (t < NB) ? cnt[t] : 0;
    sc[t] = v;
    __syncthreads();
    for (int o = 1; o < 512; o <<= 1) {
        int add = (t >= o) ? sc[t - o] : 0;
        __syncthreads();
        sc[t] += add;
        __syncthreads();
    }
    if (t < NB) {
        int e = sc[t] - v;
        off[t] = e;
        offT[blockIdx.x * 392 + t] = e;
    }
    if (t == 0) offT[blockIdx.x * 392 + NB] = m;   // sentinel = chunk size
    __syncthreads();
#pragma unroll
    for (int i = 0; i < 8; ++i) {
        int k = t + i * 512;
        if (k < m) {
            int b = dsts[i] >> BSH;
            int p = off[b] + atomicAdd(&cur[b], 1);
            // src in bits 0..16 (100000 < 2^17), node-local dst (d&255) in 17..24
            cbuf[p] = make_int2(srcs[i] | ((dsts[i] & 255) << 17), __float_as_int(ews[i]));
        }
    }
    __syncthreads();
    for (int k = t; k < m; k += 512) rec[base + k] = cbuf[k];   // coalesced
}

__device__ __forceinline__ u32 bfpack(float a, float b) {  // RNE bf16 pair
    u32 ua = __float_as_uint(a), ub = __float_as_uint(b);
    ua = (ua + 0x7FFFu + ((ua >> 16) & 1u)) >> 16;
    ub = (ub + 0x7FFFu + ((ub >> 16) & 1u)) >> 16;
    return ua | (ub << 16);
}

// Pass 2: one block per bucket. Gathers the bucket's ~4096 records from 391
// short chunk-runs via offT (thread c copies run c: ~10.5 contiguous int2),
// then histogram+wsum (2 LDS atomics/record), scan, dinv + bf16 xpb row
// build, sorted rewrite into the bucket's fixed rec2 slot [b*4800, b*4800+m).
__global__ __launch_bounds__(512) void k_sort(const int2* __restrict__ rec,
                                              const int* __restrict__ offT,
                                              int2* __restrict__ rec2,
                                              int* __restrict__ nodebase,
                                              int* __restrict__ bend,
                                              float* __restrict__ dinv,
                                              const float* __restrict__ x,
                                              u32* __restrict__ xpb) {
    __shared__ int2 buf[SORTCAP];                // 37.5 KB
    __shared__ int sc[512];
    __shared__ int cnt[256], cur[256];
    __shared__ float wsum[256], dvs[256];
    int b = blockIdx.x, t = threadIdx.x;
    // ---- run lengths + scan -> destination offsets in buf ----
    int o0 = 0, len = 0;
    if (t < NCH) {
        o0 = offT[t * 392 + b];
        len = offT[t * 392 + b + 1] - o0;
    }
    sc[t] = len;
    __syncthreads();
    for (int o = 1; o < 512; o <<= 1) {
        int add = (t >= o) ? sc[t - o] : 0;
        __syncthreads();
        sc[t] += add;
        __syncthreads();
    }
    int rdst = sc[t] - len;
    int m = min(sc[511], SORTCAP);
    if (t < 256) { cnt[t] = 0; wsum[t] = 0.f; }
    __syncthreads();
    // ---- ragged gather + histogram + wsum ----
    for (int j = 0; j < len; ++j) {
        int d = rdst + j;
        if (d >= SORTCAP) break;
        int2 r = rec[t * CHUNK + o0 + j];
        buf[d] = r;
        int loc = (r.x >> 17) & 255;
        atomicAdd(&cnt[loc], 1);
        atomicAdd(&wsum[loc], __int_as_float(r.y));
    }
    __syncthreads();
    // ---- per-node scan, dinv, nodebase, xpb row ----
    int v = (t < 256) ? cnt[t] : 0;
    sc[t] = v;
    __syncthreads();
    for (int o = 1; o < 256; o <<= 1) {
        int add = (t >= o) ? sc[t - o] : 0;
        __syncthreads();
        sc[t] += add;
        __syncthreads();
    }
    if (t < 256) {
        int e = sc[t] - v;  // exclusive prefix
        cur[t] = e;
        float dv = rsqrtf(1.0f + wsum[t]);  // +1 = self loop
        dvs[t] = dv;
        int n = (b << BSH) + t;
        if (n < NN) {
            dinv[n] = dv;
            nodebase[n] = b * SORTCAP + e;
            const float4* xr = (const float4*)(x + (long)n * TT);
            float4 v0 = xr[0], v1 = xr[1], v2 = xr[2];
            uint4* xo = (uint4*)(xpb + ((long)n << 3));
            uint4 w0, w1;
            w0.x = bfpack(v0.x * dv, v0.y * dv);
            w0.y = bfpack(v0.z * dv, v0.w * dv);
            w0.z = bfpack(v1.x * dv, v1.y * dv);
            w0.w = bfpack(v1.z * dv, v1.w * dv);
            w1.x = bfpack(v2.x * dv, v2.y * dv);
            w1.y = bfpack(v2.z * dv, v2.w * dv);
            w1.z = 0u; w1.w = 0u;
            xo[0] = w0; xo[1] = w1;
        }
    }
    if (t == 0) {
        bend[b] = b * SORTCAP + m;
        if (b == NB - 1) nodebase[NN] = b * SORTCAP + m;
    }
    __syncthreads();
    // ---- sorted rewrite ----
    for (int k = t; k < m; k += 512) {
        int2 r = buf[k];
        int loc = (r.x >> 17) & 255;
        int p = atomicAdd(&cur[loc], 1);
        float w2 = __int_as_float(r.y) * dvs[loc];  // fold dinv[dst] into weight
        rec2[b * SORTCAP + p] = make_int2(r.x & 0x1FFFF, __float_as_int(w2));
    }
}

#define BLO(w) __uint_as_float((w) << 16)
#define BHI(w) __uint_as_float((w) & 0xFFFF0000u)

// 16 lanes per node (was 8): mean degree 16 -> each lane owns ~1 edge, so
// the dependent rec2->xpb load chain per lane halves (the quantity k_fused
// has actually been bound by: invariant to VALU/occupancy/footprint, hurt
// when edge-parallelism fell (R6), helped when it rose (R1)). Epilogue: 2
// channels/lane, 4-level shfl reduce. 1.6M threads = 3125x512 exactly.
__global__ __launch_bounds__(512) void k_fused(const int* __restrict__ nodebase,
                                               const int* __restrict__ bend,
                                               const int2* __restrict__ rec2,
                                               const float* __restrict__ dinv,
                                               const u32* __restrict__ xpb,
                                               const float* __restrict__ P,
                                               const float* __restrict__ hw,
                                               const float* __restrict__ hb,
                                               float* __restrict__ out) {
    int g = blockIdx.x * 512 + threadIdx.x;
    int n = g >> 4, sub = g & 15;
    float a[TT];
#pragma unroll
    for (int q = 0; q < TT; ++q) a[q] = 0.f;
    if (sub == 0) {
        float di = dinv[n];   // self term = dinv * (bf16 row)
        const uint4* xr = (const uint4*)(xpb + ((long)n << 3));
        uint4 h0 = xr[0];
        uint2 h1 = *(const uint2*)(xr + 1);
        a[0]  = di * BLO(h0.x); a[1]  = di * BHI(h0.x);
        a[2]  = di * BLO(h0.y); a[3]  = di * BHI(h0.y);
        a[4]  = di * BLO(h0.z); a[5]  = di * BHI(h0.z);
        a[6]  = di * BLO(h0.w); a[7]  = di * BHI(h0.w);
        a[8]  = di * BLO(h1.x); a[9]  = di * BHI(h1.x);
        a[10] = di * BLO(h1.y); a[11] = di * BHI(h1.y);
    }
    int k0 = nodebase[n];
    int k1 = ((n & 255) == 255) ? bend[n >> 8] : nodebase[n + 1];
    for (int k = k0 + sub; k < k1; k += 16) {
        int2 r = rec2[k];
        float c = __int_as_float(r.y);  // = ew * dinv[dst]; dinv[src] in xpb
        const uint4* xs = (const uint4*)(xpb + ((long)r.x << 3));
        uint4 h0 = xs[0];                       // periods 0-7 (16B)
        uint2 h1 = *(const uint2*)(xs + 1);     // periods 8-11 (8B, same line)
        a[0]  = fmaf(c, BLO(h0.x), a[0]);  a[1]  = fmaf(c, BHI(h0.x), a[1]);
        a[2]  = fmaf(c, BLO(h0.y), a[2]);  a[3]  = fmaf(c, BHI(h0.y), a[3]);
        a[4]  = fmaf(c, BLO(h0.z), a[4]);  a[5]  = fmaf(c, BHI(h0.z), a[5]);
        a[6]  = fmaf(c, BLO(h0.w), a[6]);  a[7]  = fmaf(c, BHI(h0.w), a[7]);
        a[8]  = fmaf(c, BLO(h1.x), a[8]);  a[9]  = fmaf(c, BHI(h1.x), a[9]);
        a[10] = fmaf(c, BLO(h1.y), a[10]); a[11] = fmaf(c, BHI(h1.y), a[11]);
    }
    // tree-reduce the 12 accumulators across the 16 lanes of this node
#pragma unroll
    for (int q = 0; q < TT; ++q) {
        float v = a[q];
        v += __shfl_xor(v, 1);
        v += __shfl_xor(v, 2);
        v += __shfl_xor(v, 4);
        v += __shfl_xor(v, 8);
        a[q] = v;
    }
    // --- epilogue: gates + attention + head, 2 hidden channels per lane ---
    float p[TT];
#pragma unroll
    for (int q = 0; q < TT; ++q) p[q] = P[4*HH + q];
    float o = 0.f;
#pragma unroll
    for (int jj = 0; jj < 2; ++jj) {
        int j = (jj << 4) | sub;
        float Az = P[j], Bz = P[HH + j], Ah2 = P[2*HH + j], Bh2 = P[3*HH + j];
        float w = hw[j];
        float acc = 0.f;
#pragma unroll
        for (int q = 0; q < TT; ++q) {
            float xz = fmaf(a[q], Az, Bz);                   // log2-domain
            float xh = fminf(fmaf(a[q], Ah2, Bh2), 115.f);   // keep eh finite
            float ez = __builtin_amdgcn_exp2f(xz);  // e^orig_xz
            float eh = __builtin_amdgcn_exp2f(xh);  // e^(2*orig_xh)
            float den = (1.f + ez) * (eh + 1.f);
            float num = eh - 1.f;
            acc = fmaf(p[q] * num, __builtin_amdgcn_rcpf(den), acc);
        }
        o = fmaf(fmaxf(acc, 0.f), w, o);
    }
    o += __shfl_xor(o, 1);
    o += __shfl_xor(o, 2);
    o += __shfl_xor(o, 4);
    o += __shfl_xor(o, 8);
    if (sub == 0) out[n] = o + hb[0];
}

extern "C" void kernel_launch(void* const* d_in, const int* in_sizes, int n_in,
                              void* d_out, int out_size, void* d_ws, size_t ws_size,
                              hipStream_t stream) {
    const float* x    = (const float*)d_in[0];
    const int*   ei   = (const int*)d_in[1];
    const float* ew   = (const float*)d_in[2];
    const float* att  = (const float*)d_in[3];
    const float* czw  = (const float*)d_in[4];
    const float* czb  = (const float*)d_in[5];
    const float* lzw  = (const float*)d_in[6];
    const float* lzb  = (const float*)d_in[7];
    // conv_r / lin_r (d_in[8..11]) are mathematically dead: H=0 -> H*R=0, Z*H=0.
    const float* chw  = (const float*)d_in[12];
    const float* chb  = (const float*)d_in[13];
    const float* lhw  = (const float*)d_in[14];
    const float* lhb  = (const float*)d_in[15];
    const float* hw   = (const float*)d_in[16];
    const float* hb   = (const float*)d_in[17];
    float* out = (float*)d_out;

    int*  ws32     = (int*)d_ws;
    int*  offT     = ws32;                     // NCH*392 = 153272 (pad 153280)
    int*  nodebase = ws32 + 153280;            // 100001 (pad to 253312)
    int*  bend     = ws32 + 253312;            // 391 (pad to 253712)
    float* dinv    = (float*)(ws32 + 253712);  // NN
    u32*  xpb      = (u32*)(ws32 + 353712);    // NN*8 u32, 32B rows (3.2MB)
    int2* rec      = (int2*)(ws32 + 1153712);  // NE int2 (chunk-ordered)
    int2* rec2     = (int2*)(ws32 + 4353712);  // NB*4800 int2 (node-sorted)
    float* P       = (float*)(ws32 + 8107312); // 144

    k_scatter<<<NCH + 1, 512, 0, stream>>>(ei, ew, rec, offT,
                                           czw, czb, lzw, lzb, chw, chb, lhw, lhb, att, P);
    k_sort<<<NB, 512, 0, stream>>>(rec, offT, rec2, nodebase, bend, dinv, x, xpb);
    k_fused<<<(NN * 16) / 512, 512, 0, stream>>>(nodebase, bend, rec2, dinv, xpb,
                                                 P, hw, hb, out);
}